// Round 7
// baseline (155.226 us; speedup 1.0000x reference)
//
#include <hip/hip_runtime.h>
#include <hip/hip_bf16.h>

typedef __attribute__((ext_vector_type(8))) short bf16x8;  // 8 bf16 = 4 VGPRs
typedef __attribute__((ext_vector_type(4))) short short4v;
typedef __attribute__((ext_vector_type(4))) float f32x4;

#define THREADS 512
#define TILE_E 128    // edges per (8-wave) block-tile

static __device__ __forceinline__ short f2bf(float f) {
    __hip_bfloat16 h = __float2bfloat16(f);   // RNE
    return *reinterpret_cast<short*>(&h);
}
static __device__ __forceinline__ float bf2f(short s) {
    unsigned u = ((unsigned)(unsigned short)s) << 16;
    return __builtin_bit_cast(float, u);
}

// pre-pass: z (f32) -> zb (bf16), halves gather traffic
__global__ void z_to_bf16(const float* __restrict__ z, short* __restrict__ zb, int n4) {
    int i = blockIdx.x * blockDim.x + threadIdx.x;
    const int stride = gridDim.x * blockDim.x;
    for (; i < n4; i += stride) {
        float4 v = ((const float4*)z)[i];
        short4v o;
        o[0] = f2bf(v.x); o[1] = f2bf(v.y); o[2] = f2bf(v.z); o[3] = f2bf(v.w);
        ((short4v*)zb)[i] = o;
    }
}

// out[e] = relu((z[a]*z[b]) @ W1 + b1) @ W2 + b2   via bf16 MFMA
// __launch_bounds__(512,2): VGPR cap 128. (512,4) caps at 64 -> scratch spill (R4).
// Structure = R5 (passed full harness incl. post-timing) + next-tile index prefetch.
template<bool BF16Z>
__global__ __launch_bounds__(THREADS, 2) void edge_mlp_mfma(
    const float* __restrict__ z,
    const short* __restrict__ zb,    // bf16 z (used when BF16Z)
    const void* __restrict__ edge,   // int32 or int64 (detected)
    const float* __restrict__ W1,    // [128 in][128 hid] row-major
    const float* __restrict__ b1,
    const float* __restrict__ W2,
    const float* __restrict__ b2,
    float* __restrict__ out,
    int nE)
{
    __shared__ short sW1t[128 * 128];  // bf16 [n][k]; in-row bytes ^= (n&7)<<4 (32 KiB)
    __shared__ int   sI64;

    // ---- stage W1 -> bf16 [n][k] swizzled (coalesced reads, 8B LDS writes) ----
    for (int c = threadIdx.x; c < 128 * 32; c += THREADS) {
        const int n = c & 127, k4 = c >> 7;   // k = 4*k4 .. 4*k4+3
        short4v w;
        #pragma unroll
        for (int i = 0; i < 4; ++i)
            w[i] = f2bf(W1[(4 * k4 + i) * 128 + n]);
        const unsigned addr = (unsigned)(n * 256)
                            + (((unsigned)(k4 * 8)) ^ ((unsigned)(n & 7) << 4));
        *(short4v*)((char*)sW1t + addr) = w;
    }
    if (threadIdx.x < 64) {  // detect int64 indices: all odd words zero
        unsigned v = ((const unsigned*)edge)[2 * threadIdx.x + 1];
        unsigned long long nz = __ballot(v != 0u);
        if (threadIdx.x == 0) sI64 = (nz == 0ull) ? 1 : 0;
    }
    __syncthreads();
    const int i64 = sI64;
    const int* e32 = (const int*)edge;

    const int wave = threadIdx.x >> 6;
    const int lane = threadIdx.x & 63;
    const int col  = lane & 15;       // MFMA A-row / D-col selector
    const int hi   = lane >> 4;       // k-group

    const float bias2 = b2[0];
    float w2v[8], bini[8];
    #pragma unroll
    for (int nt = 0; nt < 8; ++nt) {
        w2v[nt]  = W2[nt * 16 + col];
        bini[nt] = b1[nt * 16 + col];
    }
    // B-fragment address: n = nt*16+col, in-row k-offset = (kt*64 + hi*16) ^ ((col&7)<<4)
    const unsigned mask = ((unsigned)(col & 7)) << 4;
    const unsigned rowB = (unsigned)(col * 256);
    unsigned kxor[4];
    #pragma unroll
    for (int kt = 0; kt < 4; ++kt)
        kxor[kt] = ((unsigned)(kt * 64 + hi * 16)) ^ mask;

    const int nTiles = (nE + TILE_E - 1) / TILE_E;

    if (BF16Z) {
        int tile = blockIdx.x;
        int aIdx = 0, bIdx = 0;
        if (tile < nTiles) {   // first tile's indices
            const int eRow = tile * TILE_E + (wave << 4) + col;
            const int eC = eRow < nE ? eRow : nE - 1;
            aIdx = i64 ? e32[2 * eC]        : e32[eC];
            bIdx = i64 ? e32[2 * (nE + eC)] : e32[nE + eC];
        }
        for (; tile < nTiles; tile += gridDim.x) {
            const int e0 = tile * TILE_E;

            // issue this tile's 8 gather loads immediately (idx already resident)
            const short* pa = zb + (long)aIdx * 128 + hi * 8;
            const short* pb = zb + (long)bIdx * 128 + hi * 8;
            bf16x8 av0 = *(const bf16x8*)(pa);
            bf16x8 av1 = *(const bf16x8*)(pa + 32);
            bf16x8 av2 = *(const bf16x8*)(pa + 64);
            bf16x8 av3 = *(const bf16x8*)(pa + 96);
            bf16x8 bv0 = *(const bf16x8*)(pb);
            bf16x8 bv1 = *(const bf16x8*)(pb + 32);
            bf16x8 bv2 = *(const bf16x8*)(pb + 64);
            bf16x8 bv3 = *(const bf16x8*)(pb + 96);

            // prefetch NEXT tile's indices under this tile's compute
            {
                const int tn = tile + gridDim.x;
                const int tc = tn < nTiles ? tn : tile;
                const int eRowN = tc * TILE_E + (wave << 4) + col;
                const int eCN = eRowN < nE ? eRowN : nE - 1;
                aIdx = i64 ? e32[2 * eCN]        : e32[eCN];
                bIdx = i64 ? e32[2 * (nE + eCN)] : e32[nE + eCN];
            }

            bf16x8 avs[4] = {av0, av1, av2, av3};
            bf16x8 bvs[4] = {bv0, bv1, bv2, bv3};

            f32x4 acc[8];
            #pragma unroll
            for (int nt = 0; nt < 8; ++nt) {
                acc[nt][0] = bini[nt]; acc[nt][1] = bini[nt];
                acc[nt][2] = bini[nt]; acc[nt][3] = bini[nt];
            }
            #pragma unroll
            for (int kt = 0; kt < 4; ++kt) {
                bf16x8 af;
                #pragma unroll
                for (int j = 0; j < 8; ++j)
                    af[j] = f2bf(bf2f(avs[kt][j]) * bf2f(bvs[kt][j]));
                #pragma unroll
                for (int nt = 0; nt < 8; ++nt) {
                    bf16x8 bf = *(const bf16x8*)((const char*)sW1t
                                  + rowB + (unsigned)nt * 4096 + kxor[kt]);
                    acc[nt] = __builtin_amdgcn_mfma_f32_16x16x32_bf16(af, bf, acc[nt], 0, 0, 0);
                }
            }
            #pragma unroll
            for (int r = 0; r < 4; ++r) {
                float s = 0.f;
                #pragma unroll
                for (int nt = 0; nt < 8; ++nt)
                    s = fmaf(fmaxf(acc[nt][r], 0.f), w2v[nt], s);
                s += __shfl_xor(s, 1, 64);
                s += __shfl_xor(s, 2, 64);
                s += __shfl_xor(s, 4, 64);
                s += __shfl_xor(s, 8, 64);
                const int eo = e0 + (wave << 4) + (hi << 2) + r;  // D: row=(lane>>4)*4+r
                if (col == 0 && eo < nE) out[eo] = s + bias2;
            }
        }
    } else {
        // fp32 fallback (ws too small) — R5-identical
        for (int tile = blockIdx.x; tile < nTiles; tile += gridDim.x) {
            const int e0 = tile * TILE_E;
            const int eRow = e0 + (wave << 4) + col;
            const int eC = eRow < nE ? eRow : nE - 1;
            const int aIdx = i64 ? e32[2 * eC]        : e32[eC];
            const int bIdx = i64 ? e32[2 * (nE + eC)] : e32[nE + eC];
            const float* pa = z + (long)aIdx * 128 + hi * 8;
            const float* pb = z + (long)bIdx * 128 + hi * 8;

            f32x4 acc[8];
            #pragma unroll
            for (int nt = 0; nt < 8; ++nt) {
                acc[nt][0] = bini[nt]; acc[nt][1] = bini[nt];
                acc[nt][2] = bini[nt]; acc[nt][3] = bini[nt];
            }
            #pragma unroll
            for (int kt = 0; kt < 4; ++kt) {
                float4 a0 = *(const float4*)(pa + kt * 32);
                float4 a1 = *(const float4*)(pa + kt * 32 + 4);
                float4 c0 = *(const float4*)(pb + kt * 32);
                float4 c1 = *(const float4*)(pb + kt * 32 + 4);
                bf16x8 af;
                af[0] = f2bf(a0.x * c0.x); af[1] = f2bf(a0.y * c0.y);
                af[2] = f2bf(a0.z * c0.z); af[3] = f2bf(a0.w * c0.w);
                af[4] = f2bf(a1.x * c1.x); af[5] = f2bf(a1.y * c1.y);
                af[6] = f2bf(a1.z * c1.z); af[7] = f2bf(a1.w * c1.w);
                #pragma unroll
                for (int nt = 0; nt < 8; ++nt) {
                    bf16x8 bf = *(const bf16x8*)((const char*)sW1t
                                  + rowB + (unsigned)nt * 4096 + kxor[kt]);
                    acc[nt] = __builtin_amdgcn_mfma_f32_16x16x32_bf16(af, bf, acc[nt], 0, 0, 0);
                }
            }
            #pragma unroll
            for (int r = 0; r < 4; ++r) {
                float s = 0.f;
                #pragma unroll
                for (int nt = 0; nt < 8; ++nt)
                    s = fmaf(fmaxf(acc[nt][r], 0.f), w2v[nt], s);
                s += __shfl_xor(s, 1, 64);
                s += __shfl_xor(s, 2, 64);
                s += __shfl_xor(s, 4, 64);
                s += __shfl_xor(s, 8, 64);
                const int eo = e0 + (wave << 4) + (hi << 2) + r;
                if (col == 0 && eo < nE) out[eo] = s + bias2;
            }
        }
    }
}

extern "C" void kernel_launch(void* const* d_in, const int* in_sizes, int n_in,
                              void* d_out, int out_size, void* d_ws, size_t ws_size,
                              hipStream_t stream) {
    const float* z  = (const float*)d_in[0];
    const void* edge = d_in[1];
    const float* W1 = (const float*)d_in[2];
    const float* b1 = (const float*)d_in[3];
    const float* W2 = (const float*)d_in[4];
    const float* b2 = (const float*)d_in[5];
    float* out = (float*)d_out;
    const int nE = out_size;
    const int nZ = in_sizes[0];                    // 100000*128

    const bool useBf = ws_size >= (size_t)nZ * 2;  // constant across calls -> graph-safe
    if (useBf) {
        short* zbf = (short*)d_ws;
        z_to_bf16<<<1024, 256, 0, stream>>>(z, zbf, nZ / 4);
        edge_mlp_mfma<true><<<512, THREADS, 0, stream>>>(
            z, zbf, edge, W1, b1, W2, b2, out, nE);
    } else {
        edge_mlp_mfma<false><<<512, THREADS, 0, stream>>>(
            z, nullptr, edge, W1, b1, W2, b2, out, nE);
    }
}